// Round 9
// baseline (304.037 us; speedup 1.0000x reference)
//
#include <hip/hip_runtime.h>
#include <math.h>

#define NH 12
#define SEQ 2048
#define DM 768
#define HD 64
#define NB 2
#define MT (NB * SEQ)          // 4096 rows
// Q pre-scale: 1/sqrt(64) * log2(e)  -> softmax via exp2
#define QSCL 0.18033688011112042591999058512524f

typedef short bf16x8 __attribute__((ext_vector_type(8)));
typedef float f32x16 __attribute__((ext_vector_type(16)));

__device__ __forceinline__ unsigned short bf16_rne(float x) {
    unsigned u = __float_as_uint(x);
    u += 0x7fffu + ((u >> 16) & 1u);
    return (unsigned short)(u >> 16);
}
__device__ __forceinline__ float bf16_tof(short h) {
    return __uint_as_float(((unsigned)(unsigned short)h) << 16);
}

__device__ __forceinline__ void gl_lds16(const void* g, void* s) {
    __builtin_amdgcn_global_load_lds(
        (const __attribute__((address_space(1))) unsigned int*)g,
        (__attribute__((address_space(3))) unsigned int*)s, 16, 0, 0);
}

__device__ __forceinline__ f32x16 mfma32(bf16x8 a, bf16x8 b, f32x16 c) {
    return __builtin_amdgcn_mfma_f32_32x32x16_bf16(a, b, c, 0, 0, 0);
}

// GEMM frag read: 64-B LDS rows (BK=32), 4 blocks of 16 B
__device__ __forceinline__ bf16x8 gfrag(const char* base, int row, int physblk) {
    return *(const bf16x8*)(base + row * 64 + physblk * 16);
}
// Attention frag read: 128-B LDS rows, 8 blocks of 16 B, key row&7
__device__ __forceinline__ bf16x8 afrag(const short* base, int row, int blk) {
    return *(const bf16x8*)(base + row * 64 + ((blk ^ (row & 7)) << 3));
}

// ---------------------------------------------------------------------------
// Merged pre-pass. Blocks [0,1536): x fp32 -> bf16 (key (m>>1)&3).
// Blocks [1536, 2688): W transpose+convert, z = (b-1536)/288.
// ---------------------------------------------------------------------------
__global__ __launch_bounds__(256)
void conv_all(const float* __restrict__ x,
              const float* __restrict__ Wq, const float* __restrict__ Wk,
              const float* __restrict__ Wv, const float* __restrict__ Wo,
              short* __restrict__ xg, short* __restrict__ wdst)
{
    int b = blockIdx.x;
    if (b < 1536) {
        const int idx = b * 256 + threadIdx.x;   // 4096*96
        const int m = idx / 96, bk = idx % 96;
        const float* src = x + (size_t)m * DM + bk * 8;
        float4 v0 = *(const float4*)src;
        float4 v1 = *(const float4*)(src + 4);
        const float vv[8] = {v0.x, v0.y, v0.z, v0.w, v1.x, v1.y, v1.z, v1.w};
        union { short s[8]; int4 q; } hh;
#pragma unroll
        for (int j = 0; j < 8; j++) hh.s[j] = (short)bf16_rne(vv[j]);
        const int pb = (bk & ~3) | ((bk & 3) ^ ((m >> 1) & 3));
        *(int4*)(xg + (size_t)m * DM + pb * 8) = hh.q;
    } else {
        b -= 1536;
        const int z = b / 288;
        const float* __restrict__ W = (z == 0) ? Wq : (z == 1) ? Wk : (z == 2) ? Wv : Wo;
        const int idx = (b % 288) * 256 + threadIdx.x;   // 96*768
        const int n = idx % 768, bk = idx / 768;
        union { short s[8]; int4 q; } hh;
#pragma unroll
        for (int j = 0; j < 8; j++) hh.s[j] = (short)bf16_rne(W[(size_t)(bk * 8 + j) * DM + n]);
        const int pb = (bk & ~3) | ((bk & 3) ^ ((n >> 1) & 3));
        *(int4*)(wdst + (size_t)z * 589824 + (size_t)n * DM + pb * 8) = hh.q;
    }
}

// ---------------------------------------------------------------------------
// QKV K-loop with register-prefetch pipeline (tile 64M x 128N, BK=32, 24
// iters). Global->VGPR loads issued 2 tiles ahead; VGPR->LDS ds_write 1
// tile ahead into double-buffered LDS; ONE barrier per iter and never a
// vmcnt(0) drain. SWAP=true computes Y^T (reg-rows = n).
// ---------------------------------------------------------------------------
template<bool SWAP>
__device__ __forceinline__ void qkv_loop(const char* pA, const char* pB,
                                         char* As, char* Bs,
                                         int t, f32x16* acc)
{
    const int w = t >> 6, l = t & 63;
    const int q32 = l & 31, half = l >> 5;
    const int sel = (q32 >> 1) & 3;
    const int arow  = 32 * (w & 1) + q32;
    const int brow0 = 64 * (w >> 1) + q32;

    uint4 ar[2], br0[2], br1[2];
    // prologue: tiles 0,1 -> regs; tile 0 -> LDS buf 0
    ar[0]  = *(const uint4*)(pA);
    br0[0] = *(const uint4*)(pB);
    br1[0] = *(const uint4*)(pB + 64 * 1536);
    ar[1]  = *(const uint4*)(pA + 64);
    br0[1] = *(const uint4*)(pB + 64);
    br1[1] = *(const uint4*)(pB + 64 * 1536 + 64);
    *(uint4*)(As + t * 16) = ar[0];
    *(uint4*)(Bs + t * 16) = br0[0];
    *(uint4*)(Bs + 4096 + t * 16) = br1[0];
    __syncthreads();

    for (int ki = 0; ki < 24; ki++) {
        const int cur = ki & 1;
        const char* sA = As + cur * 4096;
        const char* sB = Bs + cur * 8192;
        // prefetch tile ki+2 into the reg slot whose tile was staged last iter
        if (ki < 22) {
            const size_t cb = (size_t)(ki + 2) * 64;
            ar[cur]  = *(const uint4*)(pA + cb);
            br0[cur] = *(const uint4*)(pB + cb);
            br1[cur] = *(const uint4*)(pB + 64 * 1536 + cb);
        }
        // stage tile ki+1 (loaded one iteration ago) into the other buffer
        if (ki < 23) {
            char* dA = As + (cur ^ 1) * 4096 + t * 16;
            char* dB = Bs + (cur ^ 1) * 8192 + t * 16;
            *(uint4*)dA = ar[cur ^ 1];
            *(uint4*)dB = br0[cur ^ 1];
            *(uint4*)(dB + 4096) = br1[cur ^ 1];
        }
#pragma unroll
        for (int s = 0; s < 2; s++) {
            const int blk = (s * 2 + half) ^ sel;
            bf16x8 a  = gfrag(sA, arow, blk);
            bf16x8 b0 = gfrag(sB, brow0, blk);
            bf16x8 b1 = gfrag(sB, brow0 + 32, blk);
            if (SWAP) {
                acc[0] = mfma32(b0, a, acc[0]);
                acc[1] = mfma32(b1, a, acc[1]);
            } else {
                acc[0] = mfma32(a, b0, acc[0]);
                acc[1] = mfma32(a, b1, acc[1]);
            }
        }
        __syncthreads();
    }
}

// ---------------------------------------------------------------------------
// QKV GEMM. grid (6, 64, 3), block 256 (4 waves, each 32M x 64N).
// z<2 computes Y^T -> packed uint2 Q/K epilogue into [b][h][s][64]
// (key s&7). z==2 computes Y -> packed uint2 into V^T [b][h][hd][2048]
// (key hd&7). LDS 24 KB (double-buffered).
// ---------------------------------------------------------------------------
__global__ __launch_bounds__(256)
void gemm_qkv(const short* __restrict__ xg, const short* __restrict__ wt,
              const float* __restrict__ bq, const float* __restrict__ bkv,
              const float* __restrict__ bv,
              short* __restrict__ qg, short* __restrict__ kg, short* __restrict__ vg)
{
    const int z = blockIdx.z;
    const short* __restrict__ Bw = wt + (size_t)z * 589824;
    const float* __restrict__ bias = (z == 0) ? bq : (z == 1) ? bkv : bv;

    __shared__ char As[8192], Bs[16384];
    const int t = threadIdx.x, w = t >> 6, l = t & 63;
    const int m0 = blockIdx.y * 64, n0 = blockIdx.x * 128;
    const int q32 = l & 31, half = l >> 5;

    const char* pA = (const char*)xg + (size_t)(m0 + (t >> 2)) * 1536 + (t & 3) * 16;
    const char* pB = (const char*)Bw + (size_t)(n0 + (t >> 2)) * 1536 + (t & 3) * 16;

    f32x16 acc[2];
#pragma unroll
    for (int i = 0; i < 2; i++)
#pragma unroll
        for (int r = 0; r < 16; r++) acc[i][r] = 0.f;

    if (z == 2) {
        qkv_loop<false>(pA, pB, As, Bs, t, acc);
        // V^T epilogue: reg-rows = m (4 consecutive s) -> uint2 stores
        const int nbase = n0 + 64 * (w >> 1);
        const int h = nbase >> 6;
        const int mbase = m0 + 32 * (w & 1) + 4 * half;
        const int bb = mbase >> 11;
#pragma unroll
        for (int nt = 0; nt < 2; nt++) {
            const int hd = 32 * nt + q32;
            const float bia = bias[nbase + hd];
            short* vrow = vg + ((size_t)(bb * NH + h) * HD + hd) * SEQ;
#pragma unroll
            for (int g = 0; g < 4; g++) {
                const int ss0 = (mbase & 2047) + 8 * g;
                union { unsigned short u[4]; uint2 q; } pk;
#pragma unroll
                for (int j = 0; j < 4; j++)
                    pk.u[j] = bf16_rne(acc[nt][4 * g + j] + bia);
                const int blk = ss0 >> 3;
                const int phys = (blk & ~7) | ((blk & 7) ^ (hd & 7));
                *(uint2*)(vrow + phys * 8 + (ss0 & 7)) = pk.q;
            }
        }
    } else {
        qkv_loop<true>(pA, pB, As, Bs, t, acc);
        // Q/K epilogue: reg-rows = n (4 consecutive hd) -> uint2 stores
        short* dst = (z == 0) ? qg : kg;
        const float scl = (z == 0) ? QSCL : 1.0f;
        const int mcol = m0 + 32 * (w & 1) + q32;
        const int bb = mcol >> 11, ss = mcol & 2047;
        const int h = (n0 + 64 * (w >> 1)) >> 6;
        short* drow = dst + ((size_t)(bb * NH + h) * SEQ + ss) * HD;
#pragma unroll
        for (int nt = 0; nt < 2; nt++)
#pragma unroll
            for (int g = 0; g < 4; g++) {
                const int hd0 = 32 * nt + 8 * g + 4 * half;
                float4 b4 = *(const float4*)&bias[(h << 6) + hd0];
                const float bb4[4] = {b4.x, b4.y, b4.z, b4.w};
                union { unsigned short u[4]; uint2 q; } pk;
#pragma unroll
                for (int j = 0; j < 4; j++)
                    pk.u[j] = bf16_rne((acc[nt][4 * g + j] + bb4[j]) * scl);
                const int phys = (hd0 >> 3) ^ (ss & 7);
                *(uint2*)(drow + phys * 8 + (hd0 & 7)) = pk.q;
            }
    }
}

// ---------------------------------------------------------------------------
// MFMA flash attention (unchanged from R7): no-max softmax, K-split (z=2),
// single-barrier double-buffered K/V, S computed transposed (mfma(K,Q)) so
// P reg-rows are 4-consecutive keys -> 8 b64 P writes, truncation-packed.
// grid (16, 24, 2), block 256. LDS 48 KB -> 3 blocks/CU.
// ---------------------------------------------------------------------------
__global__ __launch_bounds__(256)
void attn_mfma(const short* __restrict__ qg, const short* __restrict__ kg,
               const short* __restrict__ vg,
               short* __restrict__ opart, float* __restrict__ lpart)
{
    __shared__ short Qs[8192];   // Q 128x64; later buf1: K = Qs[0..4095], V = Qs[4096..]
    __shared__ short Ks[4096];   // buf0 K (64 x 64, key s&7)
    __shared__ short Vt[4096];   // buf0 V^T (64 x 64, key hd&7)
    __shared__ short Ps[8192];   // 4 waves x 32(q) x 64(k), key q&7

    const int t = threadIdx.x, w = t >> 6, l = t & 63;
    const int bh = blockIdx.y, q0 = blockIdx.x * 128, ks = blockIdx.z;
    const char* qp = (const char*)(qg + (size_t)bh * SEQ * HD);
    const char* kp = (const char*)(kg + (size_t)bh * SEQ * HD);
    const char* vp = (const char*)(vg + (size_t)bh * HD * SEQ);
    const int kbase = ks * 1024;

#pragma unroll
    for (int i = 0; i < 4; i++)
        gl_lds16(qp + (size_t)(q0 + w * 32 + i * 8) * 128 + l * 16,
                 (char*)Qs + (w * 32 + i * 8) * 128);
#pragma unroll
    for (int i = 0; i < 2; i++) {
        gl_lds16(kp + (size_t)(kbase + w * 16 + i * 8) * 128 + l * 16,
                 (char*)Ks + (w * 16 + i * 8) * 128);
        gl_lds16(vp + (size_t)(w * 16 + i * 8 + (l >> 3)) * 4096 + kbase * 2 + (l & 7) * 16,
                 (char*)Vt + (w * 16 + i * 8) * 128);
    }
    __syncthreads();

    const int half = l >> 5;
    const int q = l & 31;
    bf16x8 qf[4];
#pragma unroll
    for (int s = 0; s < 4; s++)
        qf[s] = afrag(Qs, w * 32 + q, half + s * 2);
    __syncthreads();   // all waves done with Qs; it may now be overwritten

    f32x16 oacc[2], lacc;
#pragma unroll
    for (int nt = 0; nt < 2; nt++)
#pragma unroll
        for (int r = 0; r < 16; r++) oacc[nt][r] = 0.f;
#pragma unroll
    for (int r = 0; r < 16; r++) lacc[r] = 0.f;

    bf16x8 onesf;
#pragma unroll
    for (int j = 0; j < 8; j++) onesf[j] = (short)0x3F80;   // bf16 1.0

    short* psw = Ps + w * 2048;

    for (int kti = 0; kti < 16; kti++) {
        const int cur = kti & 1;
        if (kti < 15) {
            const int kb0 = kbase + (kti + 1) * 64;
            char* kd = cur ? (char*)Ks : (char*)Qs;
            char* vd = cur ? (char*)Vt : (char*)(Qs + 4096);
#pragma unroll
            for (int i = 0; i < 2; i++) {
                gl_lds16(kp + (size_t)(kb0 + w * 16 + i * 8) * 128 + l * 16,
                         kd + (w * 16 + i * 8) * 128);
                gl_lds16(vp + (size_t)(w * 16 + i * 8 + (l >> 3)) * 4096 + kb0 * 2 + (l & 7) * 16,
                         vd + (w * 16 + i * 8) * 128);
            }
        }
        const short* kc = cur ? Qs : Ks;
        const short* vc = cur ? Qs + 4096 : Vt;

        // S^T = K Q^T: reg-rows = key, cols = q  (q pre-scaled by 0.125*log2e)
        f32x16 sacc[2];
#pragma unroll
        for (int nt = 0; nt < 2; nt++)
#pragma unroll
            for (int r = 0; r < 16; r++) sacc[nt][r] = 0.f;
#pragma unroll
        for (int s = 0; s < 4; s++)
#pragma unroll
            for (int nt = 0; nt < 2; nt++) {
                bf16x8 kf = afrag(kc, nt * 32 + q, half + s * 2);
                sacc[nt] = mfma32(kf, qf[s], sacc[nt]);
            }

        // P = exp2(S^T): 4 consecutive keys per reg group -> one b64 write
#pragma unroll
        for (int nt = 0; nt < 2; nt++)
#pragma unroll
            for (int g = 0; g < 4; g++) {
                const float p0 = exp2f(sacc[nt][4 * g + 0]);
                const float p1 = exp2f(sacc[nt][4 * g + 1]);
                const float p2 = exp2f(sacc[nt][4 * g + 2]);
                const float p3 = exp2f(sacc[nt][4 * g + 3]);
                uint2 pk;
                pk.x = __builtin_amdgcn_perm(__float_as_uint(p1), __float_as_uint(p0), 0x07060302u);
                pk.y = __builtin_amdgcn_perm(__float_as_uint(p3), __float_as_uint(p2), 0x07060302u);
                *(uint2*)(psw + q * 64 + (((4 * nt + g) ^ (q & 7)) << 3) + 4 * half) = pk;
            }

        // O += P V ; l += P @ ones
#pragma unroll
        for (int s = 0; s < 4; s++) {
            bf16x8 pf = afrag(psw, q, half + s * 2);
            lacc = mfma32(pf, onesf, lacc);
#pragma unroll
            for (int nt = 0; nt < 2; nt++) {
                bf16x8 vf = afrag(vc, nt * 32 + q, half + s * 2);
                oacc[nt] = mfma32(pf, vf, oacc[nt]);
            }
        }
        __syncthreads();   // drains prefetch DMA; all waves done with cur buffer
    }

    // epilogue: unnormalized partials
    const size_t base = (size_t)(ks * 24 + bh) * SEQ;
#pragma unroll
    for (int r = 0; r < 16; r++) {
        const int row = q0 + w * 32 + (r & 3) + 8 * (r >> 2) + 4 * half;
#pragma unroll
        for (int nt = 0; nt < 2; nt++)
            opart[(base + row) * 64 + nt * 32 + q] = (short)bf16_rne(oacc[nt][r]);
        if (q == 0) lpart[base + row] = lacc[r];
    }
}

// ---------------------------------------------------------------------------
// Combine K-split partials: ag = (O0+O1)/(l0+l1), bf16, key (m>>1)&3.
// grid 1536, block 256 (thread = 8 hd of one row).
// ---------------------------------------------------------------------------
__global__ __launch_bounds__(256)
void attn_reduce(const short* __restrict__ opart, const float* __restrict__ lpart,
                 short* __restrict__ ag)
{
    const int idx = blockIdx.x * 256 + threadIdx.x;   // 49152*8
    const int cg = idx & 7, row = idx >> 3;
    const int bh = row >> 11, s = row & 2047;
    union { short s[8]; int4 q; } a, b, o;
    a.q = *(const int4*)(opart + ((size_t)bh * SEQ + s) * 64 + cg * 8);
    b.q = *(const int4*)(opart + ((size_t)(24 + bh) * SEQ + s) * 64 + cg * 8);
    const float inv = 1.0f / (lpart[(size_t)bh * SEQ + s] + lpart[(size_t)(24 + bh) * SEQ + s]);
#pragma unroll
    for (int j = 0; j < 8; j++)
        o.s[j] = (short)bf16_rne((bf16_tof(a.s[j]) + bf16_tof(b.s[j])) * inv);
    const int bb = bh / NH, h = bh % NH;
    const int m = bb * SEQ + s;
    const int blk = h * 8 + cg;
    const int phys = (blk & ~3) | ((blk & 3) ^ ((m >> 1) & 3));
    *(int4*)(ag + (size_t)m * DM + phys * 8) = o.q;
}

// ---------------------------------------------------------------------------
// Output projection: tile 64M x 64N, BK=32, grid (12, 64), block 256
// (4 waves, each 32x32). Register-prefetch pipeline (as qkv_loop), one
// barrier/iter. Computed transposed (reg-rows = n) -> float4 epilogue.
// LDS 16 KB (double-buffered).
// ---------------------------------------------------------------------------
__global__ __launch_bounds__(256)
void gemm_out(const short* __restrict__ ag, const short* __restrict__ wt3,
              const float* __restrict__ bias, float* __restrict__ out)
{
    __shared__ char As[8192], Bs[8192];
    const int t = threadIdx.x, w = t >> 6, l = t & 63;
    const int m0 = blockIdx.y * 64, n0 = blockIdx.x * 64;
    const int q32 = l & 31, half = l >> 5;
    const int sel = (q32 >> 1) & 3;

    const char* pA = (const char*)ag  + (size_t)(m0 + (t >> 2)) * 1536 + (t & 3) * 16;
    const char* pB = (const char*)wt3 + (size_t)(n0 + (t >> 2)) * 1536 + (t & 3) * 16;

    const int arow = 32 * (w & 1) + q32;
    const int brow = 32 * (w >> 1) + q32;

    f32x16 acc;
#pragma unroll
    for (int r = 0; r < 16; r++) acc[r] = 0.f;

    uint4 ar[2], br[2];
    ar[0] = *(const uint4*)(pA);
    br[0] = *(const uint4*)(pB);
    ar[1] = *(const uint4*)(pA + 64);
    br[1] = *(const uint4*)(pB + 64);
    *(uint4*)(As + t * 16) = ar[0];
    *(uint4*)(Bs + t * 16) = br[0];
    __syncthreads();

    for (int ki = 0; ki < 24; ki++) {
        const int cur = ki & 1;
        const char* sA = As + cur * 4096;
        const char* sB = Bs + cur * 4096;
        if (ki < 22) {
            const size_t cb = (size_t)(ki + 2) * 64;
            ar[cur] = *(const uint4*)(pA + cb);
            br[cur] = *(const uint4*)(pB + cb);
        }
        if (ki < 23) {
            *(uint4*)(As + (cur ^ 1) * 4096 + t * 16) = ar[cur ^ 1];
            *(uint4*)(Bs + (cur ^ 1) * 4096 + t * 16) = br[cur ^ 1];
        }
#pragma unroll
        for (int s = 0; s < 2; s++) {
            const int blk = (s * 2 + half) ^ sel;
            bf16x8 a = gfrag(sA, arow, blk);
            bf16x8 b = gfrag(sB, brow, blk);
            acc = mfma32(b, a, acc);   // reg-rows = n
        }
        __syncthreads();
    }

    const int mcol = m0 + 32 * (w & 1) + q32;
    const int nb0 = n0 + 32 * (w >> 1) + 4 * half;
#pragma unroll
    for (int g = 0; g < 4; g++) {
        const int ng = nb0 + 8 * g;
        float4 b4 = *(const float4*)&bias[ng];
        float4 o;
        o.x = acc[4 * g + 0] + b4.x;
        o.y = acc[4 * g + 1] + b4.y;
        o.z = acc[4 * g + 2] + b4.z;
        o.w = acc[4 * g + 3] + b4.w;
        *(float4*)&out[(size_t)mcol * DM + ng] = o;
    }
}

// ---------------------------------------------------------------------------
extern "C" void kernel_launch(void* const* d_in, const int* in_sizes, int n_in,
                              void* d_out, int out_size, void* d_ws, size_t ws_size,
                              hipStream_t stream)
{
    const float* x  = (const float*)d_in[0];
    const float* Wq = (const float*)d_in[1];
    const float* bq = (const float*)d_in[2];
    const float* Wk = (const float*)d_in[3];
    const float* bk = (const float*)d_in[4];
    const float* Wv = (const float*)d_in[5];
    const float* bv = (const float*)d_in[6];
    const float* Wo = (const float*)d_in[7];
    const float* bo = (const float*)d_in[8];
    float* out = (float*)d_out;

    const size_t BUF = (size_t)MT * DM;   // 3,145,728 elements
    short* xg = (short*)d_ws;
    short* qg = xg + BUF;
    short* kg = qg + BUF;
    short* vg = kg + BUF;
    short* ag = vg + BUF;
    short* wt = ag + BUF;                       // 4 * 589824
    short* opart = wt + (size_t)4 * 589824;     // 2*24*2048*64 shorts
    float* lpart = (float*)(opart + (size_t)2 * 24 * SEQ * HD);  // 2*24*2048 floats

    conv_all<<<2688, 256, 0, stream>>>(x, Wq, Wk, Wv, Wo, xg, wt);
    gemm_qkv<<<dim3(6, 64, 3), 256, 0, stream>>>(xg, wt, bq, bk, bv, qg, kg, vg);
    attn_mfma<<<dim3(16, 24, 2), 256, 0, stream>>>(qg, kg, vg, opart, lpart);
    attn_reduce<<<1536, 256, 0, stream>>>(opart, lpart, ag);
    gemm_out<<<dim3(12, 64), 256, 0, stream>>>(ag, wt + (size_t)3 * 589824, bo, out);
}

// Round 11
// 195.535 us; speedup vs baseline: 1.5549x; 1.5549x over previous
//
#include <hip/hip_runtime.h>
#include <math.h>

#define NH 12
#define SEQ 2048
#define DM 768
#define HD 64
#define NB 2
#define MT (NB * SEQ)          // 4096 rows
// Q pre-scale: 1/sqrt(64) * log2(e)  -> softmax via exp2
#define QSCL 0.18033688011112042591999058512524f

typedef short bf16x8 __attribute__((ext_vector_type(8)));
typedef float f32x16 __attribute__((ext_vector_type(16)));

__device__ __forceinline__ unsigned short bf16_rne(float x) {
    unsigned u = __float_as_uint(x);
    u += 0x7fffu + ((u >> 16) & 1u);
    return (unsigned short)(u >> 16);
}
__device__ __forceinline__ float bf16_tof(short h) {
    return __uint_as_float(((unsigned)(unsigned short)h) << 16);
}

__device__ __forceinline__ void gl_lds16(const void* g, void* s) {
    __builtin_amdgcn_global_load_lds(
        (const __attribute__((address_space(1))) unsigned int*)g,
        (__attribute__((address_space(3))) unsigned int*)s, 16, 0, 0);
}

__device__ __forceinline__ f32x16 mfma32(bf16x8 a, bf16x8 b, f32x16 c) {
    return __builtin_amdgcn_mfma_f32_32x32x16_bf16(a, b, c, 0, 0, 0);
}

// GEMM frag read: 64-B LDS rows (BK=32), 4 blocks of 16 B
__device__ __forceinline__ bf16x8 gfrag(const char* base, int row, int physblk) {
    return *(const bf16x8*)(base + row * 64 + physblk * 16);
}
// Attention frag read: 128-B LDS rows, 8 blocks of 16 B, key row&7
__device__ __forceinline__ bf16x8 afrag(const short* base, int row, int blk) {
    return *(const bf16x8*)(base + row * 64 + ((blk ^ (row & 7)) << 3));
}

// ---------------------------------------------------------------------------
// Merged pre-pass. Blocks [0,1536): x fp32 -> bf16 (key (m>>1)&3).
// Blocks [1536, 2688): W transpose+convert, z = (b-1536)/288.
// ---------------------------------------------------------------------------
__global__ __launch_bounds__(256)
void conv_all(const float* __restrict__ x,
              const float* __restrict__ Wq, const float* __restrict__ Wk,
              const float* __restrict__ Wv, const float* __restrict__ Wo,
              short* __restrict__ xg, short* __restrict__ wdst)
{
    int b = blockIdx.x;
    if (b < 1536) {
        const int idx = b * 256 + threadIdx.x;   // 4096*96
        const int m = idx / 96, bk = idx % 96;
        const float* src = x + (size_t)m * DM + bk * 8;
        float4 v0 = *(const float4*)src;
        float4 v1 = *(const float4*)(src + 4);
        const float vv[8] = {v0.x, v0.y, v0.z, v0.w, v1.x, v1.y, v1.z, v1.w};
        union { short s[8]; int4 q; } hh;
#pragma unroll
        for (int j = 0; j < 8; j++) hh.s[j] = (short)bf16_rne(vv[j]);
        const int pb = (bk & ~3) | ((bk & 3) ^ ((m >> 1) & 3));
        *(int4*)(xg + (size_t)m * DM + pb * 8) = hh.q;
    } else {
        b -= 1536;
        const int z = b / 288;
        const float* __restrict__ W = (z == 0) ? Wq : (z == 1) ? Wk : (z == 2) ? Wv : Wo;
        const int idx = (b % 288) * 256 + threadIdx.x;   // 96*768
        const int n = idx % 768, bk = idx / 768;
        union { short s[8]; int4 q; } hh;
#pragma unroll
        for (int j = 0; j < 8; j++) hh.s[j] = (short)bf16_rne(W[(size_t)(bk * 8 + j) * DM + n]);
        const int pb = (bk & ~3) | ((bk & 3) ^ ((n >> 1) & 3));
        *(int4*)(wdst + (size_t)z * 589824 + (size_t)n * DM + pb * 8) = hh.q;
    }
}

// ---------------------------------------------------------------------------
// QKV K-loop, register-prefetch pipeline, manually unrolled x2 (named
// registers; R9's dynamically-indexed slots spilled to scratch). Tile
// 64M x 128N, BK=32, 24 iters. Global->VGPR 2 tiles ahead, VGPR->LDS 1
// tile ahead, one barrier per iter, vmcnt never drained at a barrier.
// R10 BUG FIX: odd-iter prefetch guard was kb<10, which never loaded
// tile 23 (last K-chunk stale). Correct guard: kb<11.
// SWAP=true computes Y^T (reg-rows = n).
// ---------------------------------------------------------------------------
template<bool SWAP>
__device__ __forceinline__ void qkv_loop(const char* pA, const char* pB,
                                         char* As, char* Bs,
                                         int t, f32x16* acc)
{
    const int w = t >> 6, l = t & 63;
    const int q32 = l & 31, half = l >> 5;
    const int sel = (q32 >> 1) & 3;
    const int arow  = 32 * (w & 1) + q32;
    const int brow0 = 64 * (w >> 1) + q32;
    char* dA = As + t * 16;
    char* dB = Bs + t * 16;

    uint4 a0, b00, b10;   // slot 0 (even tiles)
    uint4 a1, b01, b11;   // slot 1 (odd tiles)

    // prologue: tiles 0,1 -> regs; tile 0 -> LDS buf 0
    a0  = *(const uint4*)(pA);
    b00 = *(const uint4*)(pB);
    b10 = *(const uint4*)(pB + 64 * 1536);
    a1  = *(const uint4*)(pA + 64);
    b01 = *(const uint4*)(pB + 64);
    b11 = *(const uint4*)(pB + 64 * 1536 + 64);
    *(uint4*)dA = a0;
    *(uint4*)dB = b00;
    *(uint4*)(dB + 4096) = b10;
    __syncthreads();

    auto compute = [&](const char* sA, const char* sB) {
#pragma unroll
        for (int s = 0; s < 2; s++) {
            const int blk = (s * 2 + half) ^ sel;
            bf16x8 a  = gfrag(sA, arow, blk);
            bf16x8 b0 = gfrag(sB, brow0, blk);
            bf16x8 b1 = gfrag(sB, brow0 + 32, blk);
            if (SWAP) {
                acc[0] = mfma32(b0, a, acc[0]);
                acc[1] = mfma32(b1, a, acc[1]);
            } else {
                acc[0] = mfma32(a, b0, acc[0]);
                acc[1] = mfma32(a, b1, acc[1]);
            }
        }
    };

    for (int kb = 0; kb < 12; kb++) {
        // even iter ki=2kb: compute buf0; prefetch tile 2kb+2 -> slot0;
        // stage slot1 (tile 2kb+1) -> buf1
        if (kb < 11) {
            const size_t cb = (size_t)(2 * kb + 2) * 64;
            a0  = *(const uint4*)(pA + cb);
            b00 = *(const uint4*)(pB + cb);
            b10 = *(const uint4*)(pB + 64 * 1536 + cb);
        }
        *(uint4*)(dA + 4096) = a1;
        *(uint4*)(dB + 8192) = b01;
        *(uint4*)(dB + 8192 + 4096) = b11;
        compute(As, Bs);
        __syncthreads();

        // odd iter ki=2kb+1: compute buf1; prefetch tile 2kb+3 -> slot1;
        // stage slot0 (tile 2kb+2) -> buf0
        if (kb < 11) {   // kb=10 loads tile 23 (R10 had kb<10: tile 23 never loaded)
            const size_t cb = (size_t)(2 * kb + 3) * 64;
            a1  = *(const uint4*)(pA + cb);
            b01 = *(const uint4*)(pB + cb);
            b11 = *(const uint4*)(pB + 64 * 1536 + cb);
        }
        if (kb < 11) {
            *(uint4*)dA = a0;
            *(uint4*)dB = b00;
            *(uint4*)(dB + 4096) = b10;
        }
        compute(As + 4096, Bs + 8192);
        __syncthreads();
    }
}

// ---------------------------------------------------------------------------
// QKV GEMM. grid (6, 64, 3), block 256 (4 waves, each 32M x 64N).
// z<2 computes Y^T -> packed uint2 Q/K epilogue into [b][h][s][64]
// (key s&7). z==2 computes Y -> packed uint2 into V^T [b][h][hd][2048]
// (key hd&7). LDS 24 KB (double-buffered).
// ---------------------------------------------------------------------------
__global__ __launch_bounds__(256)
void gemm_qkv(const short* __restrict__ xg, const short* __restrict__ wt,
              const float* __restrict__ bq, const float* __restrict__ bkv,
              const float* __restrict__ bv,
              short* __restrict__ qg, short* __restrict__ kg, short* __restrict__ vg)
{
    const int z = blockIdx.z;
    const short* __restrict__ Bw = wt + (size_t)z * 589824;
    const float* __restrict__ bias = (z == 0) ? bq : (z == 1) ? bkv : bv;

    __shared__ char As[8192], Bs[16384];
    const int t = threadIdx.x, w = t >> 6, l = t & 63;
    const int m0 = blockIdx.y * 64, n0 = blockIdx.x * 128;
    const int q32 = l & 31, half = l >> 5;

    const char* pA = (const char*)xg + (size_t)(m0 + (t >> 2)) * 1536 + (t & 3) * 16;
    const char* pB = (const char*)Bw + (size_t)(n0 + (t >> 2)) * 1536 + (t & 3) * 16;

    f32x16 acc[2];
#pragma unroll
    for (int i = 0; i < 2; i++)
#pragma unroll
        for (int r = 0; r < 16; r++) acc[i][r] = 0.f;

    if (z == 2) {
        qkv_loop<false>(pA, pB, As, Bs, t, acc);
        // V^T epilogue: reg-rows = m (4 consecutive s) -> uint2 stores
        const int nbase = n0 + 64 * (w >> 1);
        const int h = nbase >> 6;
        const int mbase = m0 + 32 * (w & 1) + 4 * half;
        const int bb = mbase >> 11;
#pragma unroll
        for (int nt = 0; nt < 2; nt++) {
            const int hd = 32 * nt + q32;
            const float bia = bias[nbase + hd];
            short* vrow = vg + ((size_t)(bb * NH + h) * HD + hd) * SEQ;
#pragma unroll
            for (int g = 0; g < 4; g++) {
                const int ss0 = (mbase & 2047) + 8 * g;
                union { unsigned short u[4]; uint2 q; } pk;
#pragma unroll
                for (int j = 0; j < 4; j++)
                    pk.u[j] = bf16_rne(acc[nt][4 * g + j] + bia);
                const int blk = ss0 >> 3;
                const int phys = (blk & ~7) | ((blk & 7) ^ (hd & 7));
                *(uint2*)(vrow + phys * 8 + (ss0 & 7)) = pk.q;
            }
        }
    } else {
        qkv_loop<true>(pA, pB, As, Bs, t, acc);
        // Q/K epilogue: reg-rows = n (4 consecutive hd) -> uint2 stores
        short* dst = (z == 0) ? qg : kg;
        const float scl = (z == 0) ? QSCL : 1.0f;
        const int mcol = m0 + 32 * (w & 1) + q32;
        const int bb = mcol >> 11, ss = mcol & 2047;
        const int h = (n0 + 64 * (w >> 1)) >> 6;
        short* drow = dst + ((size_t)(bb * NH + h) * SEQ + ss) * HD;
#pragma unroll
        for (int nt = 0; nt < 2; nt++)
#pragma unroll
            for (int g = 0; g < 4; g++) {
                const int hd0 = 32 * nt + 8 * g + 4 * half;
                float4 b4 = *(const float4*)&bias[(h << 6) + hd0];
                const float bb4[4] = {b4.x, b4.y, b4.z, b4.w};
                union { unsigned short u[4]; uint2 q; } pk;
#pragma unroll
                for (int j = 0; j < 4; j++)
                    pk.u[j] = bf16_rne((acc[nt][4 * g + j] + bb4[j]) * scl);
                const int phys = (hd0 >> 3) ^ (ss & 7);
                *(uint2*)(drow + phys * 8 + (hd0 & 7)) = pk.q;
            }
    }
}

// ---------------------------------------------------------------------------
// MFMA flash attention (unchanged from R7): no-max softmax, K-split (z=2),
// single-barrier double-buffered K/V, S computed transposed (mfma(K,Q)) so
// P reg-rows are 4-consecutive keys -> 8 b64 P writes, truncation-packed.
// grid (16, 24, 2), block 256. LDS 48 KB -> 3 blocks/CU.
// ---------------------------------------------------------------------------
__global__ __launch_bounds__(256)
void attn_mfma(const short* __restrict__ qg, const short* __restrict__ kg,
               const short* __restrict__ vg,
               short* __restrict__ opart, float* __restrict__ lpart)
{
    __shared__ short Qs[8192];   // Q 128x64; later buf1: K = Qs[0..4095], V = Qs[4096..]
    __shared__ short Ks[4096];   // buf0 K (64 x 64, key s&7)
    __shared__ short Vt[4096];   // buf0 V^T (64 x 64, key hd&7)
    __shared__ short Ps[8192];   // 4 waves x 32(q) x 64(k), key q&7

    const int t = threadIdx.x, w = t >> 6, l = t & 63;
    const int bh = blockIdx.y, q0 = blockIdx.x * 128, ks = blockIdx.z;
    const char* qp = (const char*)(qg + (size_t)bh * SEQ * HD);
    const char* kp = (const char*)(kg + (size_t)bh * SEQ * HD);
    const char* vp = (const char*)(vg + (size_t)bh * HD * SEQ);
    const int kbase = ks * 1024;

#pragma unroll
    for (int i = 0; i < 4; i++)
        gl_lds16(qp + (size_t)(q0 + w * 32 + i * 8) * 128 + l * 16,
                 (char*)Qs + (w * 32 + i * 8) * 128);
#pragma unroll
    for (int i = 0; i < 2; i++) {
        gl_lds16(kp + (size_t)(kbase + w * 16 + i * 8) * 128 + l * 16,
                 (char*)Ks + (w * 16 + i * 8) * 128);
        gl_lds16(vp + (size_t)(w * 16 + i * 8 + (l >> 3)) * 4096 + kbase * 2 + (l & 7) * 16,
                 (char*)Vt + (w * 16 + i * 8) * 128);
    }
    __syncthreads();

    const int half = l >> 5;
    const int q = l & 31;
    bf16x8 qf[4];
#pragma unroll
    for (int s = 0; s < 4; s++)
        qf[s] = afrag(Qs, w * 32 + q, half + s * 2);
    __syncthreads();   // all waves done with Qs; it may now be overwritten

    f32x16 oacc[2], lacc;
#pragma unroll
    for (int nt = 0; nt < 2; nt++)
#pragma unroll
        for (int r = 0; r < 16; r++) oacc[nt][r] = 0.f;
#pragma unroll
    for (int r = 0; r < 16; r++) lacc[r] = 0.f;

    bf16x8 onesf;
#pragma unroll
    for (int j = 0; j < 8; j++) onesf[j] = (short)0x3F80;   // bf16 1.0

    short* psw = Ps + w * 2048;

    for (int kti = 0; kti < 16; kti++) {
        const int cur = kti & 1;
        if (kti < 15) {
            const int kb0 = kbase + (kti + 1) * 64;
            char* kd = cur ? (char*)Ks : (char*)Qs;
            char* vd = cur ? (char*)Vt : (char*)(Qs + 4096);
#pragma unroll
            for (int i = 0; i < 2; i++) {
                gl_lds16(kp + (size_t)(kb0 + w * 16 + i * 8) * 128 + l * 16,
                         kd + (w * 16 + i * 8) * 128);
                gl_lds16(vp + (size_t)(w * 16 + i * 8 + (l >> 3)) * 4096 + kb0 * 2 + (l & 7) * 16,
                         vd + (w * 16 + i * 8) * 128);
            }
        }
        const short* kc = cur ? Qs : Ks;
        const short* vc = cur ? Qs + 4096 : Vt;

        // S^T = K Q^T: reg-rows = key, cols = q  (q pre-scaled by 0.125*log2e)
        f32x16 sacc[2];
#pragma unroll
        for (int nt = 0; nt < 2; nt++)
#pragma unroll
            for (int r = 0; r < 16; r++) sacc[nt][r] = 0.f;
#pragma unroll
        for (int s = 0; s < 4; s++)
#pragma unroll
            for (int nt = 0; nt < 2; nt++) {
                bf16x8 kf = afrag(kc, nt * 32 + q, half + s * 2);
                sacc[nt] = mfma32(kf, qf[s], sacc[nt]);
            }

        // P = exp2(S^T): 4 consecutive keys per reg group -> one b64 write
#pragma unroll
        for (int nt = 0; nt < 2; nt++)
#pragma unroll
            for (int g = 0; g < 4; g++) {
                const float p0 = exp2f(sacc[nt][4 * g + 0]);
                const float p1 = exp2f(sacc[nt][4 * g + 1]);
                const float p2 = exp2f(sacc[nt][4 * g + 2]);
                const float p3 = exp2f(sacc[nt][4 * g + 3]);
                uint2 pk;
                pk.x = __builtin_amdgcn_perm(__float_as_uint(p1), __float_as_uint(p0), 0x07060302u);
                pk.y = __builtin_amdgcn_perm(__float_as_uint(p3), __float_as_uint(p2), 0x07060302u);
                *(uint2*)(psw + q * 64 + (((4 * nt + g) ^ (q & 7)) << 3) + 4 * half) = pk;
            }

        // O += P V ; l += P @ ones
#pragma unroll
        for (int s = 0; s < 4; s++) {
            bf16x8 pf = afrag(psw, q, half + s * 2);
            lacc = mfma32(pf, onesf, lacc);
#pragma unroll
            for (int nt = 0; nt < 2; nt++) {
                bf16x8 vf = afrag(vc, nt * 32 + q, half + s * 2);
                oacc[nt] = mfma32(pf, vf, oacc[nt]);
            }
        }
        __syncthreads();   // drains prefetch DMA; all waves done with cur buffer
    }

    // epilogue: unnormalized partials
    const size_t base = (size_t)(ks * 24 + bh) * SEQ;
#pragma unroll
    for (int r = 0; r < 16; r++) {
        const int row = q0 + w * 32 + (r & 3) + 8 * (r >> 2) + 4 * half;
#pragma unroll
        for (int nt = 0; nt < 2; nt++)
            opart[(base + row) * 64 + nt * 32 + q] = (short)bf16_rne(oacc[nt][r]);
        if (q == 0) lpart[base + row] = lacc[r];
    }
}

// ---------------------------------------------------------------------------
// Combine K-split partials: ag = (O0+O1)/(l0+l1), bf16, key (m>>1)&3.
// grid 1536, block 256 (thread = 8 hd of one row).
// ---------------------------------------------------------------------------
__global__ __launch_bounds__(256)
void attn_reduce(const short* __restrict__ opart, const float* __restrict__ lpart,
                 short* __restrict__ ag)
{
    const int idx = blockIdx.x * 256 + threadIdx.x;   // 49152*8
    const int cg = idx & 7, row = idx >> 3;
    const int bh = row >> 11, s = row & 2047;
    union { short s[8]; int4 q; } a, b, o;
    a.q = *(const int4*)(opart + ((size_t)bh * SEQ + s) * 64 + cg * 8);
    b.q = *(const int4*)(opart + ((size_t)(24 + bh) * SEQ + s) * 64 + cg * 8);
    const float inv = 1.0f / (lpart[(size_t)bh * SEQ + s] + lpart[(size_t)(24 + bh) * SEQ + s]);
#pragma unroll
    for (int j = 0; j < 8; j++)
        o.s[j] = (short)bf16_rne((bf16_tof(a.s[j]) + bf16_tof(b.s[j])) * inv);
    const int bb = bh / NH, h = bh % NH;
    const int m = bb * SEQ + s;
    const int blk = h * 8 + cg;
    const int phys = (blk & ~3) | ((blk & 3) ^ ((m >> 1) & 3));
    *(int4*)(ag + (size_t)m * DM + phys * 8) = o.q;
}

// ---------------------------------------------------------------------------
// Output projection: tile 64M x 64N, BK=32, grid (12, 64), block 256
// (4 waves, each 32x32). Register-prefetch pipeline, manually unrolled x2
// (named registers, fixed guard). Computed transposed (reg-rows = n) ->
// float4 epilogue. LDS 16 KB (double-buffered).
// ---------------------------------------------------------------------------
__global__ __launch_bounds__(256)
void gemm_out(const short* __restrict__ ag, const short* __restrict__ wt3,
              const float* __restrict__ bias, float* __restrict__ out)
{
    __shared__ char As[8192], Bs[8192];
    const int t = threadIdx.x, w = t >> 6, l = t & 63;
    const int m0 = blockIdx.y * 64, n0 = blockIdx.x * 64;
    const int q32 = l & 31, half = l >> 5;
    const int sel = (q32 >> 1) & 3;

    const char* pA = (const char*)ag  + (size_t)(m0 + (t >> 2)) * 1536 + (t & 3) * 16;
    const char* pB = (const char*)wt3 + (size_t)(n0 + (t >> 2)) * 1536 + (t & 3) * 16;
    char* dA = As + t * 16;
    char* dB = Bs + t * 16;

    const int arow = 32 * (w & 1) + q32;
    const int brow = 32 * (w >> 1) + q32;

    f32x16 acc;
#pragma unroll
    for (int r = 0; r < 16; r++) acc[r] = 0.f;

    uint4 a0, b0, a1, b1;
    a0 = *(const uint4*)(pA);
    b0 = *(const uint4*)(pB);
    a1 = *(const uint4*)(pA + 64);
    b1 = *(const uint4*)(pB + 64);
    *(uint4*)dA = a0;
    *(uint4*)dB = b0;
    __syncthreads();

    for (int kb = 0; kb < 12; kb++) {
        // even iter: compute buf0; prefetch 2kb+2 -> slot0; stage slot1 -> buf1
        if (kb < 11) {
            const size_t cb = (size_t)(2 * kb + 2) * 64;
            a0 = *(const uint4*)(pA + cb);
            b0 = *(const uint4*)(pB + cb);
        }
        *(uint4*)(dA + 4096) = a1;
        *(uint4*)(dB + 4096) = b1;
#pragma unroll
        for (int s = 0; s < 2; s++) {
            const int blk = (s * 2 + half) ^ sel;
            acc = mfma32(gfrag(Bs, brow, blk), gfrag(As, arow, blk), acc);
        }
        __syncthreads();

        // odd iter: compute buf1; prefetch 2kb+3 -> slot1; stage slot0 -> buf0
        if (kb < 11) {   // kb=10 loads tile 23 (R10 bug: kb<10 skipped it)
            const size_t cb = (size_t)(2 * kb + 3) * 64;
            a1 = *(const uint4*)(pA + cb);
            b1 = *(const uint4*)(pB + cb);
        }
        if (kb < 11) {
            *(uint4*)dA = a0;
            *(uint4*)dB = b0;
        }
#pragma unroll
        for (int s = 0; s < 2; s++) {
            const int blk = (s * 2 + half) ^ sel;
            acc = mfma32(gfrag(Bs + 4096, brow, blk), gfrag(As + 4096, arow, blk), acc);
        }
        __syncthreads();
    }

    const int mcol = m0 + 32 * (w & 1) + q32;
    const int nb0 = n0 + 32 * (w >> 1) + 4 * half;
#pragma unroll
    for (int g = 0; g < 4; g++) {
        const int ng = nb0 + 8 * g;
        float4 b4 = *(const float4*)&bias[ng];
        float4 o;
        o.x = acc[4 * g + 0] + b4.x;
        o.y = acc[4 * g + 1] + b4.y;
        o.z = acc[4 * g + 2] + b4.z;
        o.w = acc[4 * g + 3] + b4.w;
        *(float4*)&out[(size_t)mcol * DM + ng] = o;
    }
}

// ---------------------------------------------------------------------------
extern "C" void kernel_launch(void* const* d_in, const int* in_sizes, int n_in,
                              void* d_out, int out_size, void* d_ws, size_t ws_size,
                              hipStream_t stream)
{
    const float* x  = (const float*)d_in[0];
    const float* Wq = (const float*)d_in[1];
    const float* bq = (const float*)d_in[2];
    const float* Wk = (const float*)d_in[3];
    const float* bk = (const float*)d_in[4];
    const float* Wv = (const float*)d_in[5];
    const float* bv = (const float*)d_in[6];
    const float* Wo = (const float*)d_in[7];
    const float* bo = (const float*)d_in[8];
    float* out = (float*)d_out;

    const size_t BUF = (size_t)MT * DM;   // 3,145,728 elements
    short* xg = (short*)d_ws;
    short* qg = xg + BUF;
    short* kg = qg + BUF;
    short* vg = kg + BUF;
    short* ag = vg + BUF;
    short* wt = ag + BUF;                       // 4 * 589824
    short* opart = wt + (size_t)4 * 589824;     // 2*24*2048*64 shorts
    float* lpart = (float*)(opart + (size_t)2 * 24 * SEQ * HD);  // 2*24*2048 floats

    conv_all<<<2688, 256, 0, stream>>>(x, Wq, Wk, Wv, Wo, xg, wt);
    gemm_qkv<<<dim3(6, 64, 3), 256, 0, stream>>>(xg, wt, bq, bk, bv, qg, kg, vg);
    attn_mfma<<<dim3(16, 24, 2), 256, 0, stream>>>(qg, kg, vg, opart, lpart);
    attn_reduce<<<1536, 256, 0, stream>>>(opart, lpart, ag);
    gemm_out<<<dim3(12, 64), 256, 0, stream>>>(ag, wt + (size_t)3 * 589824, bo, out);
}